// Round 1
// baseline (475.816 us; speedup 1.0000x reference)
//
#include <hip/hip_runtime.h>
#include <hip/hip_bf16.h>

// Problem: B=8, C=64, H=W=256 -> N=65536. All fp32.
// attn = scale * Wv @ (X^T X) @ Wk^T  (per batch, 64x64)
// A = softmax(top50-mask(attn)); M = A @ Wq
// out row n' (=r*1024+t): res[n',:] = x[n',:] + bproj + Wproj @ (X[64t:64t+64,:] @ M[r,:])

#define BATCHES 8
#define NROWS 65536
#define CDIM 64
#define BATCH_FLOATS (NROWS * CDIM)   // 4194304

__device__ __forceinline__ void fma16v(float a, const float4* p, float* acc) {
    float4 b0 = p[0], b1 = p[1], b2 = p[2], b3 = p[3];
    acc[0]  = fmaf(a, b0.x, acc[0]);  acc[1]  = fmaf(a, b0.y, acc[1]);
    acc[2]  = fmaf(a, b0.z, acc[2]);  acc[3]  = fmaf(a, b0.w, acc[3]);
    acc[4]  = fmaf(a, b1.x, acc[4]);  acc[5]  = fmaf(a, b1.y, acc[5]);
    acc[6]  = fmaf(a, b1.z, acc[6]);  acc[7]  = fmaf(a, b1.w, acc[7]);
    acc[8]  = fmaf(a, b2.x, acc[8]);  acc[9]  = fmaf(a, b2.y, acc[9]);
    acc[10] = fmaf(a, b2.z, acc[10]); acc[11] = fmaf(a, b2.w, acc[11]);
    acc[12] = fmaf(a, b3.x, acc[12]); acc[13] = fmaf(a, b3.y, acc[13]);
    acc[14] = fmaf(a, b3.z, acc[14]); acc[15] = fmaf(a, b3.w, acc[15]);
}

__device__ __forceinline__ void fma16g(float a, const float* __restrict__ p, float* acc) {
#pragma unroll
    for (int k = 0; k < 16; ++k) acc[k] = fmaf(a, p[k], acc[k]);
}

// ---------------- K1: partial Gram matrices -------------------------------
// grid (P, 8), 256 threads. Block (p,b) accumulates G over its row chunk.
__global__ __launch_bounds__(256) void k1_gram(const float* __restrict__ x,
                                               float* __restrict__ gpart,
                                               int P, int rows_per_block) {
    int p = blockIdx.x, b = blockIdx.y;
    const float* xb = x + (size_t)b * BATCH_FLOATS + (size_t)p * rows_per_block * CDIM;
    __shared__ float tile[64 * 64];
    int t = threadIdx.x;
    int i = t & 15, j = t >> 4;       // 16x16 thread grid, 4x4 output tile each
    float acc[16];
#pragma unroll
    for (int k = 0; k < 16; ++k) acc[k] = 0.f;

    int ntiles = rows_per_block >> 6;
    float4 pre[4];
    {
        const float4* s = (const float4*)xb;
#pragma unroll
        for (int u = 0; u < 4; ++u) pre[u] = s[u * 256 + t];
    }
    for (int tt = 0; tt < ntiles; ++tt) {
#pragma unroll
        for (int u = 0; u < 4; ++u) ((float4*)tile)[u * 256 + t] = pre[u];
        __syncthreads();
        if (tt + 1 < ntiles) {
            const float4* s = (const float4*)(xb + (size_t)(tt + 1) * 4096);
#pragma unroll
            for (int u = 0; u < 4; ++u) pre[u] = s[u * 256 + t];
        }
#pragma unroll
        for (int n = 0; n < 64; ++n) {
            float4 a4 = *(const float4*)&tile[n * 64 + 4 * i];
            float4 b4 = *(const float4*)&tile[n * 64 + 4 * j];
            acc[0]  = fmaf(a4.x, b4.x, acc[0]);  acc[1]  = fmaf(a4.x, b4.y, acc[1]);
            acc[2]  = fmaf(a4.x, b4.z, acc[2]);  acc[3]  = fmaf(a4.x, b4.w, acc[3]);
            acc[4]  = fmaf(a4.y, b4.x, acc[4]);  acc[5]  = fmaf(a4.y, b4.y, acc[5]);
            acc[6]  = fmaf(a4.y, b4.z, acc[6]);  acc[7]  = fmaf(a4.y, b4.w, acc[7]);
            acc[8]  = fmaf(a4.z, b4.x, acc[8]);  acc[9]  = fmaf(a4.z, b4.y, acc[9]);
            acc[10] = fmaf(a4.z, b4.z, acc[10]); acc[11] = fmaf(a4.z, b4.w, acc[11]);
            acc[12] = fmaf(a4.w, b4.x, acc[12]); acc[13] = fmaf(a4.w, b4.y, acc[13]);
            acc[14] = fmaf(a4.w, b4.z, acc[14]); acc[15] = fmaf(a4.w, b4.w, acc[15]);
        }
        __syncthreads();
    }
    float* gp = gpart + (size_t)(b * P + p) * 4096;
#pragma unroll
    for (int a = 0; a < 4; ++a)
#pragma unroll
        for (int c = 0; c < 4; ++c)
            gp[(4 * i + a) * 64 + 4 * j + c] = acc[a * 4 + c];
}

// ---------------- K2: reduce G, attn, topk-softmax, M^T -------------------
// grid (8), 256 threads (4 waves). Static LDS: 3 buffers of 64x68 floats.
#define S68 68
__global__ __launch_bounds__(256) void k2_attn(const float* __restrict__ gpart,
                                               const float* __restrict__ w_qkv,
                                               float* __restrict__ mt,
                                               int P) {
    __shared__ float smem[3 * 64 * S68];
    float* A = smem;                 // G        -> T1
    float* Bf = smem + 64 * S68;     // wkT      -> attn
    float* Cf = smem + 2 * 64 * S68; // wvT      -> AT
    int b = blockIdx.x;
    int tid = threadIdx.x;
    int lane = tid & 63;
    int w = __builtin_amdgcn_readfirstlane(tid >> 6);

    // ---- reduce partial Gram into A (layout G[c][f], stride 68) ----
    {
        const float4* gp4 = (const float4*)gpart + (size_t)b * P * 1024;
        float4 r[4];
#pragma unroll
        for (int u = 0; u < 4; ++u) r[u] = make_float4(0.f, 0.f, 0.f, 0.f);
        for (int p = 0; p < P; ++p) {
#pragma unroll
            for (int u = 0; u < 4; ++u) {
                float4 g = gp4[(size_t)p * 1024 + u * 256 + tid];
                r[u].x += g.x; r[u].y += g.y; r[u].z += g.z; r[u].w += g.w;
            }
        }
#pragma unroll
        for (int u = 0; u < 4; ++u) {
            int f4 = u * 256 + tid;
            int c = f4 >> 4, f = 4 * (f4 & 15);
            A[c * S68 + f + 0] = r[u].x; A[c * S68 + f + 1] = r[u].y;
            A[c * S68 + f + 2] = r[u].z; A[c * S68 + f + 3] = r[u].w;
        }
    }
    // ---- fill wkT (B) and wvT (C): transposed, stride 68 ----
#pragma unroll
    for (int u = 0; u < 4; ++u) {
        int f4 = u * 256 + tid;
        int d = f4 >> 4, f = 4 * (f4 & 15);
        float4 kv = ((const float4*)(w_qkv + 64 * 64))[f4];
        Bf[(f + 0) * S68 + d] = kv.x; Bf[(f + 1) * S68 + d] = kv.y;
        Bf[(f + 2) * S68 + d] = kv.z; Bf[(f + 3) * S68 + d] = kv.w;
        float4 vv = ((const float4*)(w_qkv + 128 * 64))[f4];
        Cf[(f + 0) * S68 + d] = vv.x; Cf[(f + 1) * S68 + d] = vv.y;
        Cf[(f + 2) * S68 + d] = vv.z; Cf[(f + 3) * S68 + d] = vv.w;
    }
    __syncthreads();

    // ---- T1[e][d] = sum_f G[e][f] * Wk[d][f]   (G symmetric: read G[f][e]) ----
    float acc[16];
#pragma unroll
    for (int k = 0; k < 16; ++k) acc[k] = 0.f;
    for (int f = 0; f < 64; ++f)
        fma16v(A[f * S68 + lane], (const float4*)&Bf[f * S68 + 16 * w], acc);
    __syncthreads();               // all reads of G done
#pragma unroll
    for (int k = 0; k < 16; ++k) A[lane * S68 + 16 * w + k] = acc[k];  // T1 -> A
    __syncthreads();

    // ---- attn[c][d] = scale * sum_e Wv[c][e] * T1[e][d] ----
#pragma unroll
    for (int k = 0; k < 16; ++k) acc[k] = 0.f;
    for (int e = 0; e < 64; ++e)
        fma16v(Cf[e * S68 + lane], (const float4*)&A[e * S68 + 16 * w], acc);
#pragma unroll
    for (int k = 0; k < 16; ++k) Bf[lane * S68 + 16 * w + k] = acc[k] * 0.125f; // attn -> B
    __syncthreads();

    // ---- topk(50) mask + softmax per row; write AT[d][c] -> C ----
#pragma unroll 1
    for (int k = 0; k < 16; ++k) {
        int c = 16 * w + k;
        float v = Bf[c * S68 + lane];
        bool act = true;
#pragma unroll 1
        for (int it = 0; it < 14; ++it) {   // remove 14 smallest
            float m = act ? v : INFINITY;
#pragma unroll
            for (int s = 1; s < 64; s <<= 1) m = fminf(m, __shfl_xor(m, s, 64));
            unsigned long long bal = __ballot(act && (v == m));
            int kill = 63 - __builtin_clzll(bal);   // highest index among ties
            if (lane == kill) act = false;
        }
        float mv = act ? v : -INFINITY;
#pragma unroll
        for (int s = 1; s < 64; s <<= 1) mv = fmaxf(mv, __shfl_xor(mv, s, 64));
        float e = act ? expf(v - mv) : 0.f;
        float sum = e;
#pragma unroll
        for (int s = 1; s < 64; s <<= 1) sum += __shfl_xor(sum, s, 64);
        Cf[lane * S68 + c] = e / sum;               // AT[d][c]
    }
    __syncthreads();

    // ---- M[c][e] = sum_d A[c][d] * Wq[d][e]; store MT[e][c] ----
#pragma unroll
    for (int k = 0; k < 16; ++k) acc[k] = 0.f;
    for (int d = 0; d < 64; ++d)
        fma16g(Cf[d * S68 + lane], w_qkv + d * 64 + 16 * w, acc);  // Wq uniform -> s_load
#pragma unroll
    for (int k = 0; k < 16; ++k)
        mt[(size_t)b * 4096 + (16 * w + k) * 64 + lane] = acc[k];
}

// ---------------- K3: main epilogue ---------------------------------------
// grid (1024, 8), 256 threads. Per block (t,b):
//   YY = Xc @ M^T ; OUT = Wproj @ YY ; res[r*1024+t,:] = x + bias + OUT[:,r]
__global__ __launch_bounds__(256) void k3_main(const float* __restrict__ x,
                                               const float* __restrict__ mt,
                                               const float* __restrict__ w_proj,
                                               const float* __restrict__ b_proj,
                                               float* __restrict__ out) {
    __shared__ float xcT[64 * 65];
    __shared__ float wpT[64 * 65];
    __shared__ float yy[64 * S68];
    int t = blockIdx.x, b = blockIdx.y;
    int tid = threadIdx.x;
    int lane = tid & 63;
    int w = __builtin_amdgcn_readfirstlane(tid >> 6);
    const float* xb = x + (size_t)b * BATCH_FLOATS;
    float bias = b_proj[lane];

#pragma unroll
    for (int u = 0; u < 4; ++u) {
        int f4 = u * 256 + tid;
        int p = f4 >> 4, c = 4 * (f4 & 15);
        float4 xv = ((const float4*)(xb + (size_t)t * 4096))[f4];
        xcT[(c + 0) * 65 + p] = xv.x; xcT[(c + 1) * 65 + p] = xv.y;
        xcT[(c + 2) * 65 + p] = xv.z; xcT[(c + 3) * 65 + p] = xv.w;
        float4 wv = ((const float4*)w_proj)[f4];
        wpT[(c + 0) * 65 + p] = wv.x; wpT[(c + 1) * 65 + p] = wv.y;
        wpT[(c + 2) * 65 + p] = wv.z; wpT[(c + 3) * 65 + p] = wv.w;
    }
    __syncthreads();

    // phase 1: YY[c'][r] = sum_e Xc[c'][e] * M[r][e]; lane=c', wave owns 16 r
    float acc[16];
#pragma unroll
    for (int k = 0; k < 16; ++k) acc[k] = 0.f;
    const float* mrow = mt + (size_t)b * 4096 + 16 * w;   // MT[e][r], uniform
    for (int e = 0; e < 64; ++e)
        fma16g(xcT[e * 65 + lane], mrow + e * 64, acc);
#pragma unroll
    for (int k = 0; k < 16; ++k) yy[lane * S68 + 16 * w + k] = acc[k];
    __syncthreads();

    // phase 2: OUT[c''][r] = sum_c' Wproj[c''][c'] * YY[c'][r]; lane=c''
    float acc2[16];
#pragma unroll
    for (int k = 0; k < 16; ++k) acc2[k] = 0.f;
    for (int cp = 0; cp < 64; ++cp)
        fma16v(wpT[cp * 65 + lane], (const float4*)&yy[cp * S68 + 16 * w], acc2);

    // epilogue: res[b, r*1024+t, c''] = x + bias + OUT[c''][r]
    size_t base = (size_t)b * BATCH_FLOATS;
#pragma unroll
    for (int k = 0; k < 16; ++k) {
        size_t np = (size_t)((16 * w + k) * 1024 + t);
        size_t idx = base + np * 64 + lane;
        out[idx] = x[idx] + bias + acc2[k];
    }
}

extern "C" void kernel_launch(void* const* d_in, const int* in_sizes, int n_in,
                              void* d_out, int out_size, void* d_ws, size_t ws_size,
                              hipStream_t stream) {
    (void)in_sizes; (void)n_in; (void)out_size;
    const float* x      = (const float*)d_in[0];
    const float* w_qkv  = (const float*)d_in[1];
    const float* w_proj = (const float*)d_in[2];
    const float* b_proj = (const float*)d_in[3];
    float* out = (float*)d_out;
    float* ws  = (float*)d_ws;

    float* mt    = ws;            // 8 * 4096 floats: M^T per batch (e-major)
    float* gpart = ws + 32768;    // 8 * P * 4096 floats

    size_t avail = ws_size / 4;
    int P = 32;
    while (P > 1 && (size_t)32768 + (size_t)BATCHES * P * 4096 > avail) P >>= 1;
    int rows_per_block = NROWS / P;

    k1_gram<<<dim3(P, BATCHES), 256, 0, stream>>>(x, gpart, P, rows_per_block);
    k2_attn<<<dim3(BATCHES), 256, 0, stream>>>(gpart, w_qkv, mt, P);
    k3_main<<<dim3(1024, BATCHES), 256, 0, stream>>>(x, mt, w_proj, b_proj, out);
}

// Round 3
// 408.245 us; speedup vs baseline: 1.1655x; 1.1655x over previous
//
#include <hip/hip_runtime.h>
#include <hip/hip_bf16.h>

// B=8, C=64, N=65536 (all fp32 in/out).
// attn = 0.125 * Wv @ (X^T X) @ Wk^T  per batch (64x64)
// A = softmax(top50-mask(attn)); M = A @ Wq  (emitted bf16)
// out[n'=r*1024+t, :] = x[n',:] + bproj + Wproj @ (X[64t..64t+63,:] @ M[r,:])
// GEMM cores use v_mfma_f32_16x16x32_bf16 (A[m=lane&15][k=q*8+j],
// B[n=lane&15][k=q*8+j] i.e. rows of the B^T matrix, D[row=q*4+reg][col=lane&15]).

#define BATCHES 8
#define NROWS 65536
#define CDIM 64
#define BATCH_FLOATS (NROWS * CDIM)   // 4194304

typedef __attribute__((ext_vector_type(8))) short bf16x8;
typedef __attribute__((ext_vector_type(4))) float f32x4;

__device__ __forceinline__ short f2bf(float f) {
    union { __hip_bfloat16 h; short s; } u;
    u.h = __float2bfloat16(f);
    return u.s;
}

__device__ __forceinline__ void fma16g(float a, const float* __restrict__ p, float* acc) {
#pragma unroll
    for (int k = 0; k < 16; ++k) acc[k] = fmaf(a, p[k], acc[k]);
}
__device__ __forceinline__ void fma16v(float a, const float4* p, float* acc) {
    float4 b0 = p[0], b1 = p[1], b2 = p[2], b3 = p[3];
    acc[0]  = fmaf(a, b0.x, acc[0]);  acc[1]  = fmaf(a, b0.y, acc[1]);
    acc[2]  = fmaf(a, b0.z, acc[2]);  acc[3]  = fmaf(a, b0.w, acc[3]);
    acc[4]  = fmaf(a, b1.x, acc[4]);  acc[5]  = fmaf(a, b1.y, acc[5]);
    acc[6]  = fmaf(a, b1.z, acc[6]);  acc[7]  = fmaf(a, b1.w, acc[7]);
    acc[8]  = fmaf(a, b2.x, acc[8]);  acc[9]  = fmaf(a, b2.y, acc[9]);
    acc[10] = fmaf(a, b2.z, acc[10]); acc[11] = fmaf(a, b2.w, acc[11]);
    acc[12] = fmaf(a, b3.x, acc[12]); acc[13] = fmaf(a, b3.y, acc[13]);
    acc[14] = fmaf(a, b3.z, acc[14]); acc[15] = fmaf(a, b3.w, acc[15]);
}

// ---------------- K0: zero the Gram accumulator ---------------------------
__global__ __launch_bounds__(256) void k0_zero(float* __restrict__ G) {
    int i = blockIdx.x * 256 + threadIdx.x;      // 8192 float4 = 32768 floats
    ((float4*)G)[i] = make_float4(0.f, 0.f, 0.f, 0.f);
}

// ---------------- K1: Gram via MFMA, atomic reduce ------------------------
// grid (64, 8), 256 threads (4 waves). Each block: 16 tiles of 64 rows.
__global__ __launch_bounds__(256) void k1_gram(const float* __restrict__ x,
                                               float* __restrict__ G,
                                               int ntiles) {
    __shared__ short xt[2][64 * 72];             // XT[f][n] bf16, stride 72
    int p = blockIdx.x, b = blockIdx.y;
    int tid = threadIdx.x;
    int l = tid & 63;
    int w = tid >> 6;
    int lm = l & 15, q = l >> 4;
    const float* xb = x + (size_t)b * BATCH_FLOATS + (size_t)p * ntiles * 4096;

    f32x4 acc[4];
#pragma unroll
    for (int mi = 0; mi < 4; ++mi) acc[mi] = (f32x4){0.f, 0.f, 0.f, 0.f};

    float4 pre[4];
    {
        const float4* s = (const float4*)xb;
#pragma unroll
        for (int u = 0; u < 4; ++u) pre[u] = s[u * 256 + tid];
    }
    for (int tt = 0; tt < ntiles; ++tt) {
        short* buf = xt[tt & 1];
#pragma unroll
        for (int u = 0; u < 4; ++u) {
            int idx = u * 256 + tid;
            int n = idx >> 4, f = (idx & 15) * 4;
            buf[(f + 0) * 72 + n] = f2bf(pre[u].x);
            buf[(f + 1) * 72 + n] = f2bf(pre[u].y);
            buf[(f + 2) * 72 + n] = f2bf(pre[u].z);
            buf[(f + 3) * 72 + n] = f2bf(pre[u].w);
        }
        if (tt + 1 < ntiles) {
            const float4* s = (const float4*)(xb + (size_t)(tt + 1) * 4096);
#pragma unroll
            for (int u = 0; u < 4; ++u) pre[u] = s[u * 256 + tid];
        }
        __syncthreads();   // double buffer: one barrier per tile
        bf16x8 bfrag[2];
#pragma unroll
        for (int ks = 0; ks < 2; ++ks)
            bfrag[ks] = *(const bf16x8*)&buf[(16 * w + lm) * 72 + ks * 32 + q * 8];
#pragma unroll
        for (int mi = 0; mi < 4; ++mi) {
#pragma unroll
            for (int ks = 0; ks < 2; ++ks) {
                bf16x8 af = *(const bf16x8*)&buf[(mi * 16 + lm) * 72 + ks * 32 + q * 8];
                acc[mi] = __builtin_amdgcn_mfma_f32_16x16x32_bf16(af, bfrag[ks], acc[mi], 0, 0, 0);
            }
        }
    }
    float* Gb = G + b * 4096;
#pragma unroll
    for (int mi = 0; mi < 4; ++mi)
#pragma unroll
        for (int r = 0; r < 4; ++r)
            atomicAdd(&Gb[(mi * 16 + q * 4 + r) * 64 + 16 * w + lm], acc[mi][r]);
}

// ---------------- K2: attn, rank-count topk, softmax, M(bf16) -------------
#define S68 68
__global__ __launch_bounds__(256) void k2_attn(const float* __restrict__ G,
                                               const float* __restrict__ w_qkv,
                                               ushort* __restrict__ m_bf) {
    __shared__ float A[64 * S68];   // G -> T1
    __shared__ float Bf[64 * S68];  // wkT -> attn
    __shared__ float Cf[64 * S68];  // wvT -> AT
    int b = blockIdx.x;
    int tid = threadIdx.x;
    int lane = tid & 63;
    int w = __builtin_amdgcn_readfirstlane(tid >> 6);

    {   // G -> A[c][f]
        const float4* g4 = (const float4*)(G + b * 4096);
#pragma unroll
        for (int u = 0; u < 4; ++u) {
            int idx = u * 256 + tid;
            int c = idx >> 4, f = (idx & 15) * 4;
            float4 g = g4[idx];
            A[c * S68 + f + 0] = g.x; A[c * S68 + f + 1] = g.y;
            A[c * S68 + f + 2] = g.z; A[c * S68 + f + 3] = g.w;
        }
    }
#pragma unroll
    for (int u = 0; u < 4; ++u) {   // wkT, wvT (transposed, stride 68)
        int idx = u * 256 + tid;
        int d = idx >> 4, f = (idx & 15) * 4;
        float4 kv = ((const float4*)(w_qkv + 64 * 64))[idx];
        Bf[(f + 0) * S68 + d] = kv.x; Bf[(f + 1) * S68 + d] = kv.y;
        Bf[(f + 2) * S68 + d] = kv.z; Bf[(f + 3) * S68 + d] = kv.w;
        float4 vv = ((const float4*)(w_qkv + 128 * 64))[idx];
        Cf[(f + 0) * S68 + d] = vv.x; Cf[(f + 1) * S68 + d] = vv.y;
        Cf[(f + 2) * S68 + d] = vv.z; Cf[(f + 3) * S68 + d] = vv.w;
    }
    __syncthreads();

    // T1[e][d] = sum_f G[e][f] Wk[d][f]  (G symmetric: read G[f][e])
    float acc[16];
#pragma unroll
    for (int k = 0; k < 16; ++k) acc[k] = 0.f;
    for (int f = 0; f < 64; ++f)
        fma16v(A[f * S68 + lane], (const float4*)&Bf[f * S68 + 16 * w], acc);
    __syncthreads();
#pragma unroll
    for (int k = 0; k < 16; ++k) A[lane * S68 + 16 * w + k] = acc[k];  // T1[e][d]
    __syncthreads();

    // attn[c][d] = 0.125 * sum_e Wv[c][e] T1[e][d]; acc[k]=attn[c=lane][d=16w+k]
#pragma unroll
    for (int k = 0; k < 16; ++k) acc[k] = 0.f;
    for (int e = 0; e < 64; ++e)
        fma16v(Cf[e * S68 + lane], (const float4*)&A[e * S68 + 16 * w], acc);
#pragma unroll
    for (int k = 0; k < 16; ++k) Bf[lane * S68 + 16 * w + k] = acc[k] * 0.125f; // ROW-major attn (R2 bug: was transposed)
    __syncthreads();

    // top-50 by rank count + softmax; write AT[d][c] -> Cf
#pragma unroll 1
    for (int k = 0; k < 16; ++k) {
        int c = 16 * w + k;
        float v = Bf[c * S68 + lane];
        int rank = 0;
#pragma unroll
        for (int d4 = 0; d4 < 16; ++d4) {
            float4 vv = *(const float4*)&Bf[c * S68 + 4 * d4];
            rank += (vv.x > v) || (vv.x == v && (4 * d4 + 0) < lane);
            rank += (vv.y > v) || (vv.y == v && (4 * d4 + 1) < lane);
            rank += (vv.z > v) || (vv.z == v && (4 * d4 + 2) < lane);
            rank += (vv.w > v) || (vv.w == v && (4 * d4 + 3) < lane);
        }
        bool act = rank < 50;
        float mv = act ? v : -INFINITY;
#pragma unroll
        for (int s = 1; s < 64; s <<= 1) mv = fmaxf(mv, __shfl_xor(mv, s, 64));
        float e = act ? expf(v - mv) : 0.f;
        float sum = e;
#pragma unroll
        for (int s = 1; s < 64; s <<= 1) sum += __shfl_xor(sum, s, 64);
        Cf[lane * S68 + c] = e / sum;
    }
    __syncthreads();

    // M[c][e] = sum_d A[c][d] Wq[d][e];   store bf16 row-major M[c][e]
#pragma unroll
    for (int k = 0; k < 16; ++k) acc[k] = 0.f;
    for (int d = 0; d < 64; ++d)
        fma16g(Cf[d * S68 + lane], w_qkv + d * 64 + 16 * w, acc);
    unsigned int uu[8];
#pragma unroll
    for (int i = 0; i < 8; ++i)
        uu[i] = (unsigned int)(unsigned short)f2bf(acc[2 * i]) |
                ((unsigned int)(unsigned short)f2bf(acc[2 * i + 1]) << 16);
    ushort* dst = m_bf + (size_t)b * 4096 + lane * 64 + 16 * w;
    *(uint4*)dst = make_uint4(uu[0], uu[1], uu[2], uu[3]);
    *(uint4*)(dst + 8) = make_uint4(uu[4], uu[5], uu[6], uu[7]);
}

// ---------------- K3: two MFMA GEMMs + residual epilogue ------------------
// grid (1024, 8), 256 threads.
__global__ __launch_bounds__(256) void k3_main(const float* __restrict__ x,
                                               const ushort* __restrict__ m_bf,
                                               const float* __restrict__ w_proj,
                                               const float* __restrict__ b_proj,
                                               float* __restrict__ out) {
    __shared__ short yyt[64 * 72];   // YY^T[r][c'] bf16 (B-frag layout for GEMM2)
    __shared__ float orow[64 * 68];  // OUT^T by output row [r][c'']
    int t = blockIdx.x, b = blockIdx.y;
    int tid = threadIdx.x;
    int l = tid & 63;
    int w = tid >> 6;
    int lm = l & 15, q = l >> 4;
    const float* xb = x + (size_t)b * BATCH_FLOATS;

    // B1 frags: rows of M (bf16 global)
    const ushort* mb = m_bf + (size_t)b * 4096;
    bf16x8 b1[2];
#pragma unroll
    for (int ks = 0; ks < 2; ++ks)
        b1[ks] = *(const bf16x8*)(mb + (16 * w + lm) * 64 + ks * 32 + q * 8);

    // GEMM1: YY[p][r] = sum_e Xc[p][e] M[r][e]; store YY^T (wave-local rows)
#pragma unroll
    for (int mi = 0; mi < 4; ++mi) {
        f32x4 acc = (f32x4){0.f, 0.f, 0.f, 0.f};
#pragma unroll
        for (int ks = 0; ks < 2; ++ks) {
            const float* ap = xb + (size_t)(64 * t + mi * 16 + lm) * 64 + ks * 32 + q * 8;
            float4 a0 = *(const float4*)ap, a1 = *(const float4*)(ap + 4);
            bf16x8 af;
            af[0] = f2bf(a0.x); af[1] = f2bf(a0.y); af[2] = f2bf(a0.z); af[3] = f2bf(a0.w);
            af[4] = f2bf(a1.x); af[5] = f2bf(a1.y); af[6] = f2bf(a1.z); af[7] = f2bf(a1.w);
            acc = __builtin_amdgcn_mfma_f32_16x16x32_bf16(af, b1[ks], acc, 0, 0, 0);
        }
        short* dst = &yyt[(16 * w + lm) * 72 + mi * 16 + q * 4];
        dst[0] = f2bf(acc[0]); dst[1] = f2bf(acc[1]);
        dst[2] = f2bf(acc[2]); dst[3] = f2bf(acc[3]);
    }
    // GEMM2: OUT = Wproj @ YY  (B2 = rows of YY^T, written by this same wave)
    bf16x8 b2[2];
#pragma unroll
    for (int ks = 0; ks < 2; ++ks)
        b2[ks] = *(const bf16x8*)&yyt[(16 * w + lm) * 72 + ks * 32 + q * 8];
#pragma unroll
    for (int mi = 0; mi < 4; ++mi) {
        f32x4 acc = (f32x4){0.f, 0.f, 0.f, 0.f};
#pragma unroll
        for (int ks = 0; ks < 2; ++ks) {
            const float* ap = w_proj + (mi * 16 + lm) * 64 + ks * 32 + q * 8;
            float4 a0 = *(const float4*)ap, a1 = *(const float4*)(ap + 4);
            bf16x8 af;
            af[0] = f2bf(a0.x); af[1] = f2bf(a0.y); af[2] = f2bf(a0.z); af[3] = f2bf(a0.w);
            af[4] = f2bf(a1.x); af[5] = f2bf(a1.y); af[6] = f2bf(a1.z); af[7] = f2bf(a1.w);
            acc = __builtin_amdgcn_mfma_f32_16x16x32_bf16(af, b2[ks], acc, 0, 0, 0);
        }
        *(f32x4*)&orow[(16 * w + lm) * 68 + mi * 16 + q * 4] = acc;
    }
    __syncthreads();

    // epilogue: out[b, r*1024+t, :] = x + bias + OUT  (coalesced float4)
    int c4 = tid & 15, r0 = tid >> 4;
    float4 bias = *(const float4*)(b_proj + 4 * c4);
#pragma unroll
    for (int kk = 0; kk < 4; ++kk) {
        int r = r0 + 16 * kk;
        float4 o = *(const float4*)&orow[r * 68 + 4 * c4];
        size_t idx = (size_t)b * BATCH_FLOATS + ((size_t)(r * 1024 + t)) * 64 + 4 * c4;
        float4 xv = *(const float4*)(x + idx);
        float4 res;
        res.x = xv.x + bias.x + o.x;
        res.y = xv.y + bias.y + o.y;
        res.z = xv.z + bias.z + o.z;
        res.w = xv.w + bias.w + o.w;
        *(float4*)(out + idx) = res;
    }
}

extern "C" void kernel_launch(void* const* d_in, const int* in_sizes, int n_in,
                              void* d_out, int out_size, void* d_ws, size_t ws_size,
                              hipStream_t stream) {
    (void)in_sizes; (void)n_in; (void)out_size; (void)ws_size;
    const float* x      = (const float*)d_in[0];
    const float* w_qkv  = (const float*)d_in[1];
    const float* w_proj = (const float*)d_in[2];
    const float* b_proj = (const float*)d_in[3];
    float* out = (float*)d_out;
    float* ws  = (float*)d_ws;

    float*  G    = ws;                    // 8*4096 f32 = 128 KB
    ushort* m_bf = (ushort*)(ws + 32768); // 8*4096 bf16 = 64 KB

    k0_zero<<<32, 256, 0, stream>>>(G);
    k1_gram<<<dim3(64, BATCHES), 256, 0, stream>>>(x, G, 16);
    k2_attn<<<BATCHES, 256, 0, stream>>>(G, w_qkv, m_bf);
    k3_main<<<dim3(1024, BATCHES), 256, 0, stream>>>(x, m_bf, w_proj, b_proj, out);
}